// Round 1
// baseline (1415.201 us; speedup 1.0000x reference)
//
#include <hip/hip_runtime.h>
#include <hip/hip_bf16.h>
#include <math.h>

#define N_NODES  100000
#define N_EDGES  3200000
#define N_GRAPHS 1000

// ---------- float <-> ordered uint for atomicMax on floats ----------
__device__ __forceinline__ unsigned enc_f32(float f) {
    unsigned u = __float_as_uint(f);
    return (u & 0x80000000u) ? ~u : (u | 0x80000000u);
}
__device__ __forceinline__ float dec_f32(unsigned u) {
    unsigned v = (u & 0x80000000u) ? (u & 0x7fffffffu) : ~u;
    return __uint_as_float(v);
}

// ---------- detect whether integer inputs are int64 or int32 ----------
// int64 node ids < 2^17 -> high 32 bits are all zero.
// int32 data reinterpreted as int64 -> "high" words are random node ids (mostly nonzero).
__global__ void detect_kernel(const long long* __restrict__ idx, int* __restrict__ flag) {
    int t = threadIdx.x;
    unsigned long long hi = ((unsigned long long)idx[t]) >> 32;
    unsigned long long any = __ballot(hi != 0ull);
    if (t == 0) *flag = (any == 0ull) ? 1 : 0;   // 1 => int64, 0 => int32
}

// ---------- fused node linear: q,k,v,skip = x@W* + b*, plus per-layer init ----------
template <int IN, int OUT>
__global__ __launch_bounds__(256)
void lin_kernel(const float* __restrict__ x,
                const float* __restrict__ Wq, const float* __restrict__ bq,
                const float* __restrict__ Wk, const float* __restrict__ bk,
                const float* __restrict__ Wv, const float* __restrict__ bv,
                const float* __restrict__ Ws, const float* __restrict__ bs,
                float* __restrict__ q, float* __restrict__ k,
                float* __restrict__ v, float* __restrict__ sk,
                unsigned* __restrict__ smax_enc, float* __restrict__ denom,
                float* __restrict__ agg, int n)
{
    __shared__ float w[4 * IN * OUT];
    __shared__ float b[4 * OUT];
    for (int t = threadIdx.x; t < IN * OUT; t += blockDim.x) {
        w[t]              = Wq[t];
        w[IN*OUT + t]     = Wk[t];
        w[2*IN*OUT + t]   = Wv[t];
        w[3*IN*OUT + t]   = Ws[t];
    }
    for (int t = threadIdx.x; t < OUT; t += blockDim.x) {
        b[t]         = bq[t];
        b[OUT + t]   = bk[t];
        b[2*OUT + t] = bv[t];
        b[3*OUT + t] = bs[t];
    }
    __syncthreads();

    for (int i = blockIdx.x * blockDim.x + threadIdx.x; i < n;
         i += gridDim.x * blockDim.x) {
        float xi[IN];
        #pragma unroll
        for (int r = 0; r < IN; ++r) xi[r] = x[(long long)i * IN + r];

        #pragma unroll
        for (int j = 0; j < OUT; ++j) {
            float aq = b[j], ak = b[OUT + j], av = b[2*OUT + j], as = b[3*OUT + j];
            #pragma unroll
            for (int r = 0; r < IN; ++r) {
                float xr = xi[r];
                aq += xr * w[r*OUT + j];
                ak += xr * w[IN*OUT + r*OUT + j];
                av += xr * w[2*IN*OUT + r*OUT + j];
                as += xr * w[3*IN*OUT + r*OUT + j];
            }
            long long o = (long long)i * OUT + j;
            q[o] = aq; k[o] = ak; v[o] = av; sk[o] = as;
            agg[o] = 0.f;
        }
        smax_enc[i] = 0u;     // == encode of "below any finite value"
        denom[i]    = 0.f;
    }
}

// ---------- edge pass 1: s = dot(q[dst], k[src]) * scale; atomicMax smax ----------
template <int D>
__global__ __launch_bounds__(256)
void edge_score_kernel(const int* __restrict__ idx32, const long long* __restrict__ idx64,
                       const int* __restrict__ flag,
                       const float* __restrict__ q, const float* __restrict__ k,
                       float* __restrict__ s_e, unsigned* __restrict__ smax_enc,
                       float scale)
{
    const int is64 = *flag;
    const int gpb  = blockDim.x / D;
    const int j    = threadIdx.x % D;
    for (int g = blockIdx.x * gpb + threadIdx.x / D; g < N_EDGES;
         g += gridDim.x * gpb) {
        int src = is64 ? (int)idx64[g]            : idx32[g];
        int dst = is64 ? (int)idx64[N_EDGES + g]  : idx32[N_EDGES + g];
        float p = q[(long long)dst * D + j] * k[(long long)src * D + j];
        #pragma unroll
        for (int off = D / 2; off; off >>= 1) p += __shfl_xor(p, off, D);
        if (j == 0) {
            float s = p * scale;
            s_e[g] = s;
            atomicMax(&smax_enc[dst], enc_f32(s));
        }
    }
}

// ---------- edge pass 2: e = exp(s - smax[dst]); denom += e; agg += e*v[src] ----------
template <int D>
__global__ __launch_bounds__(256)
void edge_agg_kernel(const int* __restrict__ idx32, const long long* __restrict__ idx64,
                     const int* __restrict__ flag,
                     const float* __restrict__ s_e, const unsigned* __restrict__ smax_enc,
                     const float* __restrict__ v,
                     float* __restrict__ denom, float* __restrict__ agg)
{
    const int is64 = *flag;
    const int gpb  = blockDim.x / D;
    const int j    = threadIdx.x % D;
    for (int g = blockIdx.x * gpb + threadIdx.x / D; g < N_EDGES;
         g += gridDim.x * gpb) {
        int src = is64 ? (int)idx64[g]            : idx32[g];
        int dst = is64 ? (int)idx64[N_EDGES + g]  : idx32[N_EDGES + g];
        float e = expf(s_e[g] - dec_f32(smax_enc[dst]));
        if (j == 0) atomicAdd(&denom[dst], e);
        atomicAdd(&agg[(long long)dst * D + j], e * v[(long long)src * D + j]);
    }
}

// ---------- node epilogue: h = relu(agg/max(denom,1e-16) + skip) ----------
template <int D>
__global__ __launch_bounds__(256)
void node_out_kernel(const float* __restrict__ agg, const float* __restrict__ denom,
                     const float* __restrict__ sk, float* __restrict__ h, int n)
{
    long long total = (long long)n * D;
    for (long long t = (long long)blockIdx.x * blockDim.x + threadIdx.x; t < total;
         t += (long long)gridDim.x * blockDim.x) {
        int i = (int)(t / D);
        float dn = fmaxf(denom[i], 1e-16f);
        float val = agg[t] / dn + sk[t];
        h[t] = fmaxf(val, 0.f);
    }
}

// ---------- pooling ----------
__global__ void pool_zero_kernel(float* __restrict__ pool, float* __restrict__ cnt) {
    int t = blockIdx.x * blockDim.x + threadIdx.x;
    if (t < N_GRAPHS * 32) pool[t] = 0.f;
    if (t < N_GRAPHS)      cnt[t]  = 0.f;
}

__global__ __launch_bounds__(256)
void pool_kernel(const int* __restrict__ b32, const long long* __restrict__ b64,
                 const int* __restrict__ flag,
                 const float* __restrict__ h, float* __restrict__ pool,
                 float* __restrict__ cnt)
{
    const int is64 = *flag;
    const int gpb  = blockDim.x / 32;
    const int j    = threadIdx.x % 32;
    for (int i = blockIdx.x * gpb + threadIdx.x / 32; i < N_NODES;
         i += gridDim.x * gpb) {
        int b = is64 ? (int)b64[i] : b32[i];
        atomicAdd(&pool[b * 32 + j], h[(long long)i * 32 + j]);
        if (j == 0) atomicAdd(&cnt[b], 1.f);
    }
}

// ---------- final MLP: out = relu(mean @ Wf1 + bf1) @ Wf2 + bf2 ----------
__global__ __launch_bounds__(64)
void mlp_kernel(const float* __restrict__ pool, const float* __restrict__ cnt,
                const float* __restrict__ Wf1, const float* __restrict__ bf1,
                const float* __restrict__ Wf2, const float* __restrict__ bf2,
                float* __restrict__ out)
{
    int g = blockIdx.x;
    int h = threadIdx.x;            // 64 threads = 64 hidden units
    __shared__ float m[32];
    if (h < 32) {
        float c = fmaxf(cnt[g], 1.f);
        m[h] = pool[g * 32 + h] / c;
    }
    __syncthreads();
    float acc = bf1[h];
    #pragma unroll
    for (int r = 0; r < 32; ++r) acc += m[r] * Wf1[r * 64 + h];
    float hid = fmaxf(acc, 0.f);
    float c = hid * Wf2[h];
    #pragma unroll
    for (int off = 32; off; off >>= 1) c += __shfl_xor(c, off, 64);
    if (h == 0) out[g] = c + bf2[0];
}

extern "C" void kernel_launch(void* const* d_in, const int* in_sizes, int n_in,
                              void* d_out, int out_size, void* d_ws, size_t ws_size,
                              hipStream_t stream) {
    const float* x = (const float*)d_in[0];
    const void*  edge_index = d_in[1];
    const void*  batch      = d_in[2];
    const float* Wq1 = (const float*)d_in[3];  const float* bq1 = (const float*)d_in[4];
    const float* Wk1 = (const float*)d_in[5];  const float* bk1 = (const float*)d_in[6];
    const float* Wv1 = (const float*)d_in[7];  const float* bv1 = (const float*)d_in[8];
    const float* Ws1 = (const float*)d_in[9];  const float* bs1 = (const float*)d_in[10];
    const float* Wq2 = (const float*)d_in[11]; const float* bq2 = (const float*)d_in[12];
    const float* Wk2 = (const float*)d_in[13]; const float* bk2 = (const float*)d_in[14];
    const float* Wv2 = (const float*)d_in[15]; const float* bv2 = (const float*)d_in[16];
    const float* Ws2 = (const float*)d_in[17]; const float* bs2 = (const float*)d_in[18];
    const float* Wf1 = (const float*)d_in[19]; const float* bf1 = (const float*)d_in[20];
    const float* Wf2 = (const float*)d_in[21]; const float* bf2 = (const float*)d_in[22];
    float* out = (float*)d_out;

    // ---------------- workspace layout (bytes) ----------------
    char* ws = (char*)d_ws;
    size_t off = 0;
    auto carve = [&](size_t bytes) {
        char* p = ws + off;
        off = (off + bytes + 255) & ~(size_t)255;
        return p;
    };
    int*      flag  = (int*)      carve(16);
    float*    qb    = (float*)    carve((size_t)N_NODES * 32 * 4);
    float*    kb    = (float*)    carve((size_t)N_NODES * 32 * 4);
    float*    vb    = (float*)    carve((size_t)N_NODES * 32 * 4);
    float*    skb   = (float*)    carve((size_t)N_NODES * 32 * 4);
    float*    agg   = (float*)    carve((size_t)N_NODES * 32 * 4);
    unsigned* smax  = (unsigned*) carve((size_t)N_NODES * 4);
    float*    denom = (float*)    carve((size_t)N_NODES * 4);
    float*    s_e   = (float*)    carve((size_t)N_EDGES * 4);
    float*    h1    = (float*)    carve((size_t)N_NODES * 16 * 4);
    float*    h2    = (float*)    carve((size_t)N_NODES * 32 * 4);
    float*    pool  = (float*)    carve((size_t)N_GRAPHS * 32 * 4);
    float*    cnt   = (float*)    carve((size_t)N_GRAPHS * 4);
    (void)ws_size; (void)in_sizes; (void)n_in; (void)out_size;

    const int* ei32 = (const int*)edge_index;
    const long long* ei64 = (const long long*)edge_index;
    const int* b32 = (const int*)batch;
    const long long* b64 = (const long long*)batch;

    const dim3 blk(256);
    const dim3 edge_grid(2048);
    const dim3 node_grid((N_NODES + 255) / 256);
    const dim3 elem_grid(2048);

    // 0. index dtype detect
    detect_kernel<<<1, 64, 0, stream>>>(ei64, flag);

    // ---- layer 1 (11 -> 16) ----
    lin_kernel<11, 16><<<node_grid, blk, 0, stream>>>(
        x, Wq1, bq1, Wk1, bk1, Wv1, bv1, Ws1, bs1,
        qb, kb, vb, skb, smax, denom, agg, N_NODES);
    edge_score_kernel<16><<<edge_grid, blk, 0, stream>>>(
        ei32, ei64, flag, qb, kb, s_e, smax, 0.25f);
    edge_agg_kernel<16><<<edge_grid, blk, 0, stream>>>(
        ei32, ei64, flag, s_e, smax, vb, denom, agg);
    node_out_kernel<16><<<elem_grid, blk, 0, stream>>>(agg, denom, skb, h1, N_NODES);

    // ---- layer 2 (16 -> 32) ----
    lin_kernel<16, 32><<<node_grid, blk, 0, stream>>>(
        h1, Wq2, bq2, Wk2, bk2, Wv2, bv2, Ws2, bs2,
        qb, kb, vb, skb, smax, denom, agg, N_NODES);
    edge_score_kernel<32><<<edge_grid, blk, 0, stream>>>(
        ei32, ei64, flag, qb, kb, s_e, smax, 0.17677669529663688f);
    edge_agg_kernel<32><<<edge_grid, blk, 0, stream>>>(
        ei32, ei64, flag, s_e, smax, vb, denom, agg);
    node_out_kernel<32><<<elem_grid, blk, 0, stream>>>(agg, denom, skb, h2, N_NODES);

    // ---- pooling + MLP ----
    pool_zero_kernel<<<(N_GRAPHS * 32 + 255) / 256, blk, 0, stream>>>(pool, cnt);
    pool_kernel<<<edge_grid, blk, 0, stream>>>(b32, b64, flag, h2, pool, cnt);
    mlp_kernel<<<N_GRAPHS, 64, 0, stream>>>(pool, cnt, Wf1, bf1, Wf2, bf2, out);
}

// Round 2
// 897.620 us; speedup vs baseline: 1.5766x; 1.5766x over previous
//
#include <hip/hip_runtime.h>
#include <hip/hip_bf16.h>
#include <math.h>

#define N_NODES  100000
#define N_EDGES  3200000
#define N_GRAPHS 1000
#define SCAN_CHUNK 1024
#define SCAN_NB ((N_NODES + SCAN_CHUNK - 1) / SCAN_CHUNK)

// ---------- detect whether integer inputs are int64 or int32 ----------
__global__ void detect_kernel(const long long* __restrict__ idx, int* __restrict__ flag) {
    int t = threadIdx.x;
    unsigned long long hi = ((unsigned long long)idx[t]) >> 32;
    unsigned long long any = __ballot(hi != 0ull);
    if (t == 0) *flag = (any == 0ull) ? 1 : 0;   // 1 => int64, 0 => int32
}

// ---------- zero deg / pool / cnt ----------
__global__ __launch_bounds__(256)
void zero_kernel(unsigned* __restrict__ deg, float* __restrict__ pool,
                 float* __restrict__ cnt) {
    int t = blockIdx.x * blockDim.x + threadIdx.x;
    if (t < N_NODES)      deg[t]  = 0u;
    if (t < N_GRAPHS*32)  pool[t] = 0.f;
    if (t < N_GRAPHS)     cnt[t]  = 0.f;
}

// ---------- histogram of dst degrees; also stash dst as int32 ----------
__global__ __launch_bounds__(256)
void hist_kernel(const int* __restrict__ idx32, const long long* __restrict__ idx64,
                 const int* __restrict__ flag,
                 unsigned* __restrict__ deg, int* __restrict__ dst32) {
    const int is64 = *flag;
    for (int e = blockIdx.x * blockDim.x + threadIdx.x; e < N_EDGES;
         e += gridDim.x * blockDim.x) {
        int d = is64 ? (int)idx64[N_EDGES + e] : idx32[N_EDGES + e];
        dst32[e] = d;
        atomicAdd(&deg[d], 1u);
    }
}

// ---------- 3-phase exclusive scan of deg -> row_start ----------
__global__ __launch_bounds__(256)
void scan1_kernel(const unsigned* __restrict__ deg, unsigned* __restrict__ scan_tmp,
                  unsigned* __restrict__ blk_sums) {
    __shared__ unsigned sh[256];
    int b = blockIdx.x, t = threadIdx.x;
    int base = b * SCAN_CHUNK + t * 4;
    unsigned v0=0,v1=0,v2=0,v3=0;
    if (base+0 < N_NODES) v0 = deg[base+0];
    if (base+1 < N_NODES) v1 = deg[base+1];
    if (base+2 < N_NODES) v2 = deg[base+2];
    if (base+3 < N_NODES) v3 = deg[base+3];
    unsigned s = v0+v1+v2+v3;
    sh[t] = s;
    __syncthreads();
    for (int off = 1; off < 256; off <<= 1) {
        unsigned val = (t >= off) ? sh[t-off] : 0u;
        __syncthreads();
        sh[t] += val;
        __syncthreads();
    }
    unsigned excl = sh[t] - s;
    if (base+0 < N_NODES) scan_tmp[base+0] = excl;
    if (base+1 < N_NODES) scan_tmp[base+1] = excl + v0;
    if (base+2 < N_NODES) scan_tmp[base+2] = excl + v0 + v1;
    if (base+3 < N_NODES) scan_tmp[base+3] = excl + v0 + v1 + v2;
    if (t == 255) blk_sums[b] = sh[255];
}

__global__ void scan2_kernel(unsigned* __restrict__ blk_sums) {
    if (threadIdx.x == 0) {
        unsigned acc = 0;
        for (int i = 0; i < SCAN_NB; ++i) { unsigned t = blk_sums[i]; blk_sums[i] = acc; acc += t; }
    }
}

__global__ __launch_bounds__(256)
void scan3_kernel(const unsigned* __restrict__ scan_tmp, const unsigned* __restrict__ blk_sums,
                  int* __restrict__ row_start, int* __restrict__ cursor) {
    int i = blockIdx.x * blockDim.x + threadIdx.x;
    if (i < N_NODES) {
        int rs = (int)(scan_tmp[i] + blk_sums[i / SCAN_CHUNK]);
        row_start[i] = rs;
        cursor[i]    = rs;
    }
    if (i == 0) row_start[N_NODES] = N_EDGES;
}

// ---------- scatter edges into dst-sorted order ----------
__global__ __launch_bounds__(256)
void scatter_kernel(const int* __restrict__ idx32, const long long* __restrict__ idx64,
                    const int* __restrict__ flag, const int* __restrict__ dst32,
                    int* __restrict__ cursor, int* __restrict__ sorted_src) {
    const int is64 = *flag;
    for (int e = blockIdx.x * blockDim.x + threadIdx.x; e < N_EDGES;
         e += gridDim.x * blockDim.x) {
        int s = is64 ? (int)idx64[e] : idx32[e];
        int d = dst32[e];
        int pos = atomicAdd(&cursor[d], 1);
        sorted_src[pos] = s;
    }
}

// ---------- fused node linear: q,k,v,skip = x@W* + b* ----------
template <int IN, int OUT>
__global__ __launch_bounds__(256)
void lin_kernel(const float* __restrict__ x,
                const float* __restrict__ Wq, const float* __restrict__ bq,
                const float* __restrict__ Wk, const float* __restrict__ bk,
                const float* __restrict__ Wv, const float* __restrict__ bv,
                const float* __restrict__ Ws, const float* __restrict__ bs,
                float* __restrict__ q, float* __restrict__ k,
                float* __restrict__ v, float* __restrict__ sk, int n)
{
    __shared__ float w[4 * IN * OUT];
    __shared__ float b[4 * OUT];
    for (int t = threadIdx.x; t < IN * OUT; t += blockDim.x) {
        w[t]            = Wq[t];
        w[IN*OUT + t]   = Wk[t];
        w[2*IN*OUT + t] = Wv[t];
        w[3*IN*OUT + t] = Ws[t];
    }
    for (int t = threadIdx.x; t < OUT; t += blockDim.x) {
        b[t]         = bq[t];
        b[OUT + t]   = bk[t];
        b[2*OUT + t] = bv[t];
        b[3*OUT + t] = bs[t];
    }
    __syncthreads();

    for (int i = blockIdx.x * blockDim.x + threadIdx.x; i < n;
         i += gridDim.x * blockDim.x) {
        float xi[IN];
        #pragma unroll
        for (int r = 0; r < IN; ++r) xi[r] = x[(long long)i * IN + r];

        #pragma unroll
        for (int j = 0; j < OUT; ++j) {
            float aq = b[j], ak = b[OUT + j], av = b[2*OUT + j], as = b[3*OUT + j];
            #pragma unroll
            for (int r = 0; r < IN; ++r) {
                float xr = xi[r];
                aq += xr * w[r*OUT + j];
                ak += xr * w[IN*OUT + r*OUT + j];
                av += xr * w[2*IN*OUT + r*OUT + j];
                as += xr * w[3*IN*OUT + r*OUT + j];
            }
            long long o = (long long)i * OUT + j;
            q[o] = aq; k[o] = ak; v[o] = av; sk[o] = as;
        }
    }
}

// ---------- fused per-node attention (online softmax over CSR segment) ----------
template <int D, bool POOL>
__global__ __launch_bounds__(256)
void fused_attn_kernel(const float* __restrict__ q, const float* __restrict__ k,
                       const float* __restrict__ v, const float* __restrict__ sk,
                       const int* __restrict__ row_start, const int* __restrict__ sorted_src,
                       const int* __restrict__ b32, const long long* __restrict__ b64,
                       const int* __restrict__ flag, float scale,
                       float* __restrict__ h, float* __restrict__ pool,
                       float* __restrict__ cnt)
{
    const int gpb = 256 / D;
    const int j = threadIdx.x % D;
    int i = blockIdx.x * gpb + threadIdx.x / D;
    if (i >= N_NODES) return;

    float qj = q[(long long)i * D + j] * scale;   // fold 1/sqrt(d) into q
    int beg = row_start[i], end = row_start[i + 1];

    float m = -INFINITY, denom = 0.f, acc = 0.f;
    for (int e = beg; e < end; ++e) {
        int s = sorted_src[e];
        float kj = k[(long long)s * D + j];
        float p = qj * kj;
        #pragma unroll
        for (int off = D / 2; off; off >>= 1) p += __shfl_xor(p, off, D);
        float mn = fmaxf(m, p);
        float so = __expf(m - mn);     // first iter: exp(-inf)=0
        float pe = __expf(p - mn);
        denom = denom * so + pe;
        acc   = acc   * so + pe * v[(long long)s * D + j];
        m = mn;
    }
    float outv = acc / fmaxf(denom, 1e-16f) + sk[(long long)i * D + j];
    outv = fmaxf(outv, 0.f);

    if (POOL) {
        int b = (*flag) ? (int)b64[i] : b32[i];
        atomicAdd(&pool[b * 32 + j], outv);
        if (j == 0) atomicAdd(&cnt[b], 1.f);
    } else {
        h[(long long)i * D + j] = outv;
    }
}

// ---------- final MLP: out = relu(mean @ Wf1 + bf1) @ Wf2 + bf2 ----------
__global__ __launch_bounds__(64)
void mlp_kernel(const float* __restrict__ pool, const float* __restrict__ cnt,
                const float* __restrict__ Wf1, const float* __restrict__ bf1,
                const float* __restrict__ Wf2, const float* __restrict__ bf2,
                float* __restrict__ out)
{
    int g = blockIdx.x;
    int h = threadIdx.x;            // 64 threads = 64 hidden units
    __shared__ float m[32];
    if (h < 32) {
        float c = fmaxf(cnt[g], 1.f);
        m[h] = pool[g * 32 + h] / c;
    }
    __syncthreads();
    float acc = bf1[h];
    #pragma unroll
    for (int r = 0; r < 32; ++r) acc += m[r] * Wf1[r * 64 + h];
    float hid = fmaxf(acc, 0.f);
    float c = hid * Wf2[h];
    #pragma unroll
    for (int off = 32; off; off >>= 1) c += __shfl_xor(c, off, 64);
    if (h == 0) out[g] = c + bf2[0];
}

extern "C" void kernel_launch(void* const* d_in, const int* in_sizes, int n_in,
                              void* d_out, int out_size, void* d_ws, size_t ws_size,
                              hipStream_t stream) {
    const float* x = (const float*)d_in[0];
    const void*  edge_index = d_in[1];
    const void*  batch      = d_in[2];
    const float* Wq1 = (const float*)d_in[3];  const float* bq1 = (const float*)d_in[4];
    const float* Wk1 = (const float*)d_in[5];  const float* bk1 = (const float*)d_in[6];
    const float* Wv1 = (const float*)d_in[7];  const float* bv1 = (const float*)d_in[8];
    const float* Ws1 = (const float*)d_in[9];  const float* bs1 = (const float*)d_in[10];
    const float* Wq2 = (const float*)d_in[11]; const float* bq2 = (const float*)d_in[12];
    const float* Wk2 = (const float*)d_in[13]; const float* bk2 = (const float*)d_in[14];
    const float* Wv2 = (const float*)d_in[15]; const float* bv2 = (const float*)d_in[16];
    const float* Ws2 = (const float*)d_in[17]; const float* bs2 = (const float*)d_in[18];
    const float* Wf1 = (const float*)d_in[19]; const float* bf1 = (const float*)d_in[20];
    const float* Wf2 = (const float*)d_in[21]; const float* bf2 = (const float*)d_in[22];
    float* out = (float*)d_out;

    // ---------------- workspace layout ----------------
    char* ws = (char*)d_ws;
    size_t off = 0;
    auto carve = [&](size_t bytes) {
        char* p = ws + off;
        off = (off + bytes + 255) & ~(size_t)255;
        return p;
    };
    int*      flag     = (int*)      carve(16);
    float*    qb       = (float*)    carve((size_t)N_NODES * 32 * 4);
    float*    kb       = (float*)    carve((size_t)N_NODES * 32 * 4);
    float*    vb       = (float*)    carve((size_t)N_NODES * 32 * 4);
    float*    skb      = (float*)    carve((size_t)N_NODES * 32 * 4);
    float*    h1       = (float*)    carve((size_t)N_NODES * 16 * 4);
    unsigned* deg      = (unsigned*) carve((size_t)N_NODES * 4);
    unsigned* scan_tmp = (unsigned*) carve((size_t)N_NODES * 4);
    unsigned* blk_sums = (unsigned*) carve((size_t)SCAN_NB * 4);
    int*      row_start= (int*)      carve((size_t)(N_NODES + 1) * 4);
    int*      cursor   = (int*)      carve((size_t)N_NODES * 4);
    int*      dst32    = (int*)      carve((size_t)N_EDGES * 4);
    int*      srt_src  = (int*)      carve((size_t)N_EDGES * 4);
    float*    pool     = (float*)    carve((size_t)N_GRAPHS * 32 * 4);
    float*    cnt      = (float*)    carve((size_t)N_GRAPHS * 4);
    (void)ws_size; (void)in_sizes; (void)n_in; (void)out_size;

    const int* ei32 = (const int*)edge_index;
    const long long* ei64 = (const long long*)edge_index;
    const int* b32 = (const int*)batch;
    const long long* b64 = (const long long*)batch;

    const dim3 blk(256);
    const dim3 edge_grid(2048);
    const dim3 node_grid((N_NODES + 255) / 256);

    // ---- CSR build (shared by both layers) ----
    detect_kernel<<<1, 64, 0, stream>>>(ei64, flag);
    zero_kernel<<<node_grid, blk, 0, stream>>>(deg, pool, cnt);
    hist_kernel<<<edge_grid, blk, 0, stream>>>(ei32, ei64, flag, deg, dst32);
    scan1_kernel<<<SCAN_NB, blk, 0, stream>>>(deg, scan_tmp, blk_sums);
    scan2_kernel<<<1, 64, 0, stream>>>(blk_sums);
    scan3_kernel<<<node_grid, blk, 0, stream>>>(scan_tmp, blk_sums, row_start, cursor);
    scatter_kernel<<<edge_grid, blk, 0, stream>>>(ei32, ei64, flag, dst32, cursor, srt_src);

    // ---- layer 1 (11 -> 16) ----
    lin_kernel<11, 16><<<node_grid, blk, 0, stream>>>(
        x, Wq1, bq1, Wk1, bk1, Wv1, bv1, Ws1, bs1, qb, kb, vb, skb, N_NODES);
    fused_attn_kernel<16, false><<<(N_NODES + 15) / 16, blk, 0, stream>>>(
        qb, kb, vb, skb, row_start, srt_src, b32, b64, flag, 0.25f,
        h1, pool, cnt);

    // ---- layer 2 (16 -> 32), pooling fused into epilogue ----
    lin_kernel<16, 32><<<node_grid, blk, 0, stream>>>(
        h1, Wq2, bq2, Wk2, bk2, Wv2, bv2, Ws2, bs2, qb, kb, vb, skb, N_NODES);
    fused_attn_kernel<32, true><<<(N_NODES + 7) / 8, blk, 0, stream>>>(
        qb, kb, vb, skb, row_start, srt_src, b32, b64, flag, 0.17677669529663688f,
        nullptr, pool, cnt);

    // ---- MLP head ----
    mlp_kernel<<<N_GRAPHS, 64, 0, stream>>>(pool, cnt, Wf1, bf1, Wf2, bf2, out);
}

// Round 3
// 825.282 us; speedup vs baseline: 1.7148x; 1.0877x over previous
//
#include <hip/hip_runtime.h>
#include <hip/hip_bf16.h>
#include <math.h>

#define N_NODES  100000
#define N_EDGES  3200000
#define N_GRAPHS 1000
#define SCAN_CHUNK 1024
#define SCAN_NB ((N_NODES + SCAN_CHUNK - 1) / SCAN_CHUNK)

// ---------- detect whether integer inputs are int64 or int32 ----------
__global__ void detect_kernel(const long long* __restrict__ idx, int* __restrict__ flag) {
    int t = threadIdx.x;
    unsigned long long hi = ((unsigned long long)idx[t]) >> 32;
    unsigned long long any = __ballot(hi != 0ull);
    if (t == 0) *flag = (any == 0ull) ? 1 : 0;   // 1 => int64, 0 => int32
}

// ---------- zero deg / pool / cnt ----------
__global__ __launch_bounds__(256)
void zero_kernel(unsigned* __restrict__ deg, float* __restrict__ pool,
                 float* __restrict__ cnt) {
    int t = blockIdx.x * blockDim.x + threadIdx.x;
    if (t < N_NODES)      deg[t]  = 0u;
    if (t < N_GRAPHS*32)  pool[t] = 0.f;
    if (t < N_GRAPHS)     cnt[t]  = 0.f;
}

// ---------- histogram of dst degrees; also stash dst as int32 ----------
__global__ __launch_bounds__(256)
void hist_kernel(const int* __restrict__ idx32, const long long* __restrict__ idx64,
                 const int* __restrict__ flag,
                 unsigned* __restrict__ deg, int* __restrict__ dst32) {
    const int is64 = *flag;
    for (int e = blockIdx.x * blockDim.x + threadIdx.x; e < N_EDGES;
         e += gridDim.x * blockDim.x) {
        int d = is64 ? (int)idx64[N_EDGES + e] : idx32[N_EDGES + e];
        dst32[e] = d;
        atomicAdd(&deg[d], 1u);
    }
}

// ---------- 3-phase exclusive scan of deg -> row_start ----------
__global__ __launch_bounds__(256)
void scan1_kernel(const unsigned* __restrict__ deg, unsigned* __restrict__ scan_tmp,
                  unsigned* __restrict__ blk_sums) {
    __shared__ unsigned sh[256];
    int b = blockIdx.x, t = threadIdx.x;
    int base = b * SCAN_CHUNK + t * 4;
    unsigned v0=0,v1=0,v2=0,v3=0;
    if (base+0 < N_NODES) v0 = deg[base+0];
    if (base+1 < N_NODES) v1 = deg[base+1];
    if (base+2 < N_NODES) v2 = deg[base+2];
    if (base+3 < N_NODES) v3 = deg[base+3];
    unsigned s = v0+v1+v2+v3;
    sh[t] = s;
    __syncthreads();
    for (int off = 1; off < 256; off <<= 1) {
        unsigned val = (t >= off) ? sh[t-off] : 0u;
        __syncthreads();
        sh[t] += val;
        __syncthreads();
    }
    unsigned excl = sh[t] - s;
    if (base+0 < N_NODES) scan_tmp[base+0] = excl;
    if (base+1 < N_NODES) scan_tmp[base+1] = excl + v0;
    if (base+2 < N_NODES) scan_tmp[base+2] = excl + v0 + v1;
    if (base+3 < N_NODES) scan_tmp[base+3] = excl + v0 + v1 + v2;
    if (t == 255) blk_sums[b] = sh[255];
}

__global__ void scan2_kernel(unsigned* __restrict__ blk_sums) {
    if (threadIdx.x == 0) {
        unsigned acc = 0;
        for (int i = 0; i < SCAN_NB; ++i) { unsigned t = blk_sums[i]; blk_sums[i] = acc; acc += t; }
    }
}

__global__ __launch_bounds__(256)
void scan3_kernel(const unsigned* __restrict__ scan_tmp, const unsigned* __restrict__ blk_sums,
                  int* __restrict__ row_start, int* __restrict__ cursor) {
    int i = blockIdx.x * blockDim.x + threadIdx.x;
    if (i < N_NODES) {
        int rs = (int)(scan_tmp[i] + blk_sums[i / SCAN_CHUNK]);
        row_start[i] = rs;
        cursor[i]    = rs;
    }
    if (i == 0) row_start[N_NODES] = N_EDGES;
}

// ---------- scatter edges into dst-sorted order ----------
__global__ __launch_bounds__(256)
void scatter_kernel(const int* __restrict__ idx32, const long long* __restrict__ idx64,
                    const int* __restrict__ flag, const int* __restrict__ dst32,
                    int* __restrict__ cursor, int* __restrict__ sorted_src) {
    const int is64 = *flag;
    for (int e = blockIdx.x * blockDim.x + threadIdx.x; e < N_EDGES;
         e += gridDim.x * blockDim.x) {
        int s = is64 ? (int)idx64[e] : idx32[e];
        int d = dst32[e];
        int pos = atomicAdd(&cursor[d], 1);
        sorted_src[pos] = s;
    }
}

// ---------- fused node linear: q = (x@Wq+bq)*scale; kv interleaved; sk ----------
template <int IN, int OUT>
__global__ __launch_bounds__(256)
void lin_kernel(const float* __restrict__ x,
                const float* __restrict__ Wq, const float* __restrict__ bq,
                const float* __restrict__ Wk, const float* __restrict__ bk,
                const float* __restrict__ Wv, const float* __restrict__ bv,
                const float* __restrict__ Ws, const float* __restrict__ bs,
                float scale,
                float* __restrict__ q, float* __restrict__ kv,
                float* __restrict__ sk, int n)
{
    __shared__ float w[4 * IN * OUT];
    __shared__ float b[4 * OUT];
    for (int t = threadIdx.x; t < IN * OUT; t += blockDim.x) {
        w[t]            = Wq[t];
        w[IN*OUT + t]   = Wk[t];
        w[2*IN*OUT + t] = Wv[t];
        w[3*IN*OUT + t] = Ws[t];
    }
    for (int t = threadIdx.x; t < OUT; t += blockDim.x) {
        b[t]         = bq[t];
        b[OUT + t]   = bk[t];
        b[2*OUT + t] = bv[t];
        b[3*OUT + t] = bs[t];
    }
    __syncthreads();

    for (int i = blockIdx.x * blockDim.x + threadIdx.x; i < n;
         i += gridDim.x * blockDim.x) {
        float xi[IN];
        #pragma unroll
        for (int r = 0; r < IN; ++r) xi[r] = x[(size_t)i * IN + r];

        #pragma unroll
        for (int j = 0; j < OUT; ++j) {
            float aq = b[j], ak = b[OUT + j], av = b[2*OUT + j], as = b[3*OUT + j];
            #pragma unroll
            for (int r = 0; r < IN; ++r) {
                float xr = xi[r];
                aq += xr * w[r*OUT + j];
                ak += xr * w[IN*OUT + r*OUT + j];
                av += xr * w[2*IN*OUT + r*OUT + j];
                as += xr * w[3*IN*OUT + r*OUT + j];
            }
            q[(size_t)i * OUT + j]              = aq * scale;
            kv[(size_t)i * 2 * OUT + j]         = ak;
            kv[(size_t)i * 2 * OUT + OUT + j]   = av;
            sk[(size_t)i * OUT + j]             = as;
        }
    }
}

// ---------- fused per-node attention (float4 lanes, online softmax, unroll-2) ----------
template <int D, bool POOL>
__global__ __launch_bounds__(256)
void fused_attn_kernel(const float* __restrict__ q, const float* __restrict__ kv,
                       const float* __restrict__ sk,
                       const int* __restrict__ row_start, const int* __restrict__ sorted_src,
                       const int* __restrict__ b32, const long long* __restrict__ b64,
                       const int* __restrict__ flag,
                       float* __restrict__ h, float* __restrict__ pool,
                       float* __restrict__ cnt)
{
    constexpr int L = D / 4;             // lanes per group, one float4 each
    const int gpb = 256 / L;
    const int lj = threadIdx.x & (L - 1);
    int i = blockIdx.x * gpb + threadIdx.x / L;
    if (i >= N_NODES) return;

    const float4 qj = *(const float4*)(q + (size_t)i * D + lj * 4);
    const int beg = row_start[i], end = row_start[i + 1];

    float m = -INFINITY, denom = 0.f;
    float4 acc = make_float4(0.f, 0.f, 0.f, 0.f);

    for (int e = beg; e < end; e += 2) {
        int s0 = sorted_src[e];
        int s1 = (e + 1 < end) ? sorted_src[e + 1] : s0;
        const float4* kv0 = (const float4*)(kv + (size_t)s0 * (2 * D));
        const float4* kv1 = (const float4*)(kv + (size_t)s1 * (2 * D));
        float4 k0 = kv0[lj],     k1 = kv1[lj];
        float4 v0 = kv0[L + lj], v1 = kv1[L + lj];

        float p0 = k0.x*qj.x + k0.y*qj.y + k0.z*qj.z + k0.w*qj.w;
        float p1 = k1.x*qj.x + k1.y*qj.y + k1.z*qj.z + k1.w*qj.w;
        #pragma unroll
        for (int off = L / 2; off; off >>= 1) {
            p0 += __shfl_xor(p0, off, L);
            p1 += __shfl_xor(p1, off, L);
        }
        if (e + 1 >= end) p1 = -INFINITY;

        float mn = fmaxf(m, fmaxf(p0, p1));
        float so = __expf(m  - mn);     // first iter: exp(-inf)=0
        float e0 = __expf(p0 - mn);
        float e1 = __expf(p1 - mn);
        denom = denom * so + e0 + e1;
        acc.x = acc.x * so + e0 * v0.x + e1 * v1.x;
        acc.y = acc.y * so + e0 * v0.y + e1 * v1.y;
        acc.z = acc.z * so + e0 * v0.z + e1 * v1.z;
        acc.w = acc.w * so + e0 * v0.w + e1 * v1.w;
        m = mn;
    }

    float dn = 1.f / fmaxf(denom, 1e-16f);
    const float4 skv = *(const float4*)(sk + (size_t)i * D + lj * 4);
    float4 o;
    o.x = fmaxf(acc.x * dn + skv.x, 0.f);
    o.y = fmaxf(acc.y * dn + skv.y, 0.f);
    o.z = fmaxf(acc.z * dn + skv.z, 0.f);
    o.w = fmaxf(acc.w * dn + skv.w, 0.f);

    if (POOL) {
        int b = (*flag) ? (int)b64[i] : b32[i];
        float* pb = pool + b * 32 + lj * 4;
        atomicAdd(pb + 0, o.x);
        atomicAdd(pb + 1, o.y);
        atomicAdd(pb + 2, o.z);
        atomicAdd(pb + 3, o.w);
        if (lj == 0) atomicAdd(&cnt[b], 1.f);
    } else {
        *(float4*)(h + (size_t)i * D + lj * 4) = o;
    }
}

// ---------- final MLP: out = relu(mean @ Wf1 + bf1) @ Wf2 + bf2 ----------
__global__ __launch_bounds__(64)
void mlp_kernel(const float* __restrict__ pool, const float* __restrict__ cnt,
                const float* __restrict__ Wf1, const float* __restrict__ bf1,
                const float* __restrict__ Wf2, const float* __restrict__ bf2,
                float* __restrict__ out)
{
    int g = blockIdx.x;
    int h = threadIdx.x;            // 64 threads = 64 hidden units
    __shared__ float m[32];
    if (h < 32) {
        float c = fmaxf(cnt[g], 1.f);
        m[h] = pool[g * 32 + h] / c;
    }
    __syncthreads();
    float acc = bf1[h];
    #pragma unroll
    for (int r = 0; r < 32; ++r) acc += m[r] * Wf1[r * 64 + h];
    float hid = fmaxf(acc, 0.f);
    float c = hid * Wf2[h];
    #pragma unroll
    for (int off = 32; off; off >>= 1) c += __shfl_xor(c, off, 64);
    if (h == 0) out[g] = c + bf2[0];
}

extern "C" void kernel_launch(void* const* d_in, const int* in_sizes, int n_in,
                              void* d_out, int out_size, void* d_ws, size_t ws_size,
                              hipStream_t stream) {
    const float* x = (const float*)d_in[0];
    const void*  edge_index = d_in[1];
    const void*  batch      = d_in[2];
    const float* Wq1 = (const float*)d_in[3];  const float* bq1 = (const float*)d_in[4];
    const float* Wk1 = (const float*)d_in[5];  const float* bk1 = (const float*)d_in[6];
    const float* Wv1 = (const float*)d_in[7];  const float* bv1 = (const float*)d_in[8];
    const float* Ws1 = (const float*)d_in[9];  const float* bs1 = (const float*)d_in[10];
    const float* Wq2 = (const float*)d_in[11]; const float* bq2 = (const float*)d_in[12];
    const float* Wk2 = (const float*)d_in[13]; const float* bk2 = (const float*)d_in[14];
    const float* Wv2 = (const float*)d_in[15]; const float* bv2 = (const float*)d_in[16];
    const float* Ws2 = (const float*)d_in[17]; const float* bs2 = (const float*)d_in[18];
    const float* Wf1 = (const float*)d_in[19]; const float* bf1 = (const float*)d_in[20];
    const float* Wf2 = (const float*)d_in[21]; const float* bf2 = (const float*)d_in[22];
    float* out = (float*)d_out;

    // ---------------- workspace layout ----------------
    char* ws = (char*)d_ws;
    size_t off = 0;
    auto carve = [&](size_t bytes) {
        char* p = ws + off;
        off = (off + bytes + 255) & ~(size_t)255;
        return p;
    };
    int*      flag     = (int*)      carve(16);
    float*    qb       = (float*)    carve((size_t)N_NODES * 32 * 4);
    float*    kvb      = (float*)    carve((size_t)N_NODES * 64 * 4);
    float*    skb      = (float*)    carve((size_t)N_NODES * 32 * 4);
    float*    h1       = (float*)    carve((size_t)N_NODES * 16 * 4);
    unsigned* deg      = (unsigned*) carve((size_t)N_NODES * 4);
    unsigned* scan_tmp = (unsigned*) carve((size_t)N_NODES * 4);
    unsigned* blk_sums = (unsigned*) carve((size_t)SCAN_NB * 4);
    int*      row_start= (int*)      carve((size_t)(N_NODES + 1) * 4);
    int*      cursor   = (int*)      carve((size_t)N_NODES * 4);
    int*      dst32    = (int*)      carve((size_t)N_EDGES * 4);
    int*      srt_src  = (int*)      carve((size_t)N_EDGES * 4);
    float*    pool     = (float*)    carve((size_t)N_GRAPHS * 32 * 4);
    float*    cnt      = (float*)    carve((size_t)N_GRAPHS * 4);
    (void)ws_size; (void)in_sizes; (void)n_in; (void)out_size;

    const int* ei32 = (const int*)edge_index;
    const long long* ei64 = (const long long*)edge_index;
    const int* b32 = (const int*)batch;
    const long long* b64 = (const long long*)batch;

    const dim3 blk(256);
    const dim3 edge_grid(2048);
    const dim3 node_grid((N_NODES + 255) / 256);

    // ---- CSR build (shared by both layers) ----
    detect_kernel<<<1, 64, 0, stream>>>(ei64, flag);
    zero_kernel<<<node_grid, blk, 0, stream>>>(deg, pool, cnt);
    hist_kernel<<<edge_grid, blk, 0, stream>>>(ei32, ei64, flag, deg, dst32);
    scan1_kernel<<<SCAN_NB, blk, 0, stream>>>(deg, scan_tmp, blk_sums);
    scan2_kernel<<<1, 64, 0, stream>>>(blk_sums);
    scan3_kernel<<<node_grid, blk, 0, stream>>>(scan_tmp, blk_sums, row_start, cursor);
    scatter_kernel<<<edge_grid, blk, 0, stream>>>(ei32, ei64, flag, dst32, cursor, srt_src);

    // ---- layer 1 (11 -> 16) ----
    lin_kernel<11, 16><<<node_grid, blk, 0, stream>>>(
        x, Wq1, bq1, Wk1, bk1, Wv1, bv1, Ws1, bs1, 0.25f,
        qb, kvb, skb, N_NODES);
    fused_attn_kernel<16, false><<<(N_NODES + 63) / 64, blk, 0, stream>>>(
        qb, kvb, skb, row_start, srt_src, b32, b64, flag, h1, pool, cnt);

    // ---- layer 2 (16 -> 32), pooling fused into epilogue ----
    lin_kernel<16, 32><<<node_grid, blk, 0, stream>>>(
        h1, Wq2, bq2, Wk2, bk2, Wv2, bv2, Ws2, bs2, 0.17677669529663688f,
        qb, kvb, skb, N_NODES);
    fused_attn_kernel<32, true><<<(N_NODES + 31) / 32, blk, 0, stream>>>(
        qb, kvb, skb, row_start, srt_src, b32, b64, flag, nullptr, pool, cnt);

    // ---- MLP head ----
    mlp_kernel<<<N_GRAPHS, 64, 0, stream>>>(pool, cnt, Wf1, bf1, Wf2, bf2, out);
}

// Round 4
// 475.839 us; speedup vs baseline: 2.9741x; 1.7344x over previous
//
#include <hip/hip_runtime.h>
#include <hip/hip_bf16.h>
#include <math.h>

#define N_NODES  100000
#define N_EDGES  3200000
#define N_GRAPHS 1000
#define NBKT ((N_NODES + 255) >> 8)       // 391 buckets of 256 nodes
#define PCHUNK 4096
#define EPT (PCHUNK / 256)                // 16 edges per thread

// ---------- detect whether integer inputs are int64 or int32 ----------
__global__ void detect_kernel(const long long* __restrict__ idx, int* __restrict__ flag) {
    int t = threadIdx.x;
    unsigned long long hi = ((unsigned long long)idx[t]) >> 32;
    unsigned long long any = __ballot(hi != 0ull);
    if (t == 0) *flag = (any == 0ull) ? 1 : 0;   // 1 => int64, 0 => int32
}

// ---------- zero bcnt / pool / cnt ----------
__global__ __launch_bounds__(256)
void zero_kernel(unsigned* __restrict__ bcnt, float* __restrict__ pool,
                 float* __restrict__ cnt) {
    int t = blockIdx.x * blockDim.x + threadIdx.x;
    if (t < NBKT)         bcnt[t] = 0u;
    if (t < N_GRAPHS*32)  pool[t] = 0.f;
    if (t < N_GRAPHS)     cnt[t]  = 0.f;
}

// ---------- bucket histogram (LDS-staged) ----------
__global__ __launch_bounds__(256)
void bhist_kernel(const int* __restrict__ idx32, const long long* __restrict__ idx64,
                  const int* __restrict__ flag, unsigned* __restrict__ bcnt) {
    __shared__ unsigned lh[NBKT];
    const int is64 = *flag;
    for (int b = threadIdx.x; b < NBKT; b += 256) lh[b] = 0u;
    __syncthreads();
    for (int e = blockIdx.x * blockDim.x + threadIdx.x; e < N_EDGES;
         e += gridDim.x * blockDim.x) {
        int d = is64 ? (int)idx64[N_EDGES + e] : idx32[N_EDGES + e];
        atomicAdd(&lh[((unsigned)d) >> 8], 1u);
    }
    __syncthreads();
    for (int b = threadIdx.x; b < NBKT; b += 256)
        if (lh[b]) atomicAdd(&bcnt[b], lh[b]);
}

// ---------- single-block exclusive scan of bucket counts ----------
__global__ __launch_bounds__(512)
void bscan_kernel(const unsigned* __restrict__ bcnt, unsigned* __restrict__ bstart,
                  unsigned* __restrict__ bcur) {
    __shared__ unsigned sc[512];
    int t = threadIdx.x;
    sc[t] = (t < NBKT) ? bcnt[t] : 0u;
    __syncthreads();
    for (int off = 1; off < 512; off <<= 1) {
        unsigned v = (t >= off) ? sc[t - off] : 0u;
        __syncthreads();
        sc[t] += v;
        __syncthreads();
    }
    if (t < NBKT) {
        unsigned excl = sc[t] - bcnt[t];
        bstart[t] = excl;
        bcur[t]   = excl;
    }
    if (t == 0) bstart[NBKT] = N_EDGES;
}

// ---------- partition edges into bucket segments (LDS counting sort per chunk) ----------
// packed pair: (dst & 255) << 17 | src    (src < 2^17)
__global__ __launch_bounds__(256)
void partition_kernel(const int* __restrict__ idx32, const long long* __restrict__ idx64,
                      const int* __restrict__ flag,
                      unsigned* __restrict__ bcur, unsigned* __restrict__ pairs) {
    __shared__ unsigned       sbuf[PCHUNK];   // 16 KB packed pairs, chunk-sorted
    __shared__ unsigned short sbkt[PCHUNK];   // 8 KB bucket per slot
    __shared__ unsigned lhist[NBKT];
    __shared__ unsigned lscan[512];
    __shared__ unsigned gbase[NBKT];
    const int is64 = *flag;
    const int t = threadIdx.x;
    const int base = blockIdx.x * PCHUNK;
    const int nval = min(PCHUNK, N_EDGES - base);

    for (int b = t; b < NBKT; b += 256) lhist[b] = 0u;
    __syncthreads();

    unsigned pr[EPT]; unsigned short br[EPT]; unsigned short rr[EPT];
    #pragma unroll
    for (int r = 0; r < EPT; ++r) {
        int e = base + r * 256 + t;
        br[r] = 0xFFFF;
        if (e < N_EDGES) {
            int s = is64 ? (int)idx64[e]           : idx32[e];
            int d = is64 ? (int)idx64[N_EDGES + e] : idx32[N_EDGES + e];
            unsigned bk = ((unsigned)d) >> 8;
            pr[r] = (((unsigned)d & 255u) << 17) | (unsigned)s;
            br[r] = (unsigned short)bk;
            rr[r] = (unsigned short)atomicAdd(&lhist[bk], 1u);
        }
    }
    __syncthreads();

    // inclusive scan of lhist over 512 padded slots
    lscan[t]       = (t < NBKT)       ? lhist[t]       : 0u;
    lscan[t + 256] = (t + 256 < NBKT) ? lhist[t + 256] : 0u;
    __syncthreads();
    for (int off = 1; off < 512; off <<= 1) {
        unsigned v0 = (t >= off)       ? lscan[t - off]       : 0u;
        unsigned v1 = (t + 256 >= off) ? lscan[t + 256 - off] : 0u;
        __syncthreads();
        lscan[t] += v0; lscan[t + 256] += v1;
        __syncthreads();
    }

    // reserve global space per bucket
    for (int b = t; b < NBKT; b += 256) {
        unsigned c = lhist[b];
        if (c) gbase[b] = atomicAdd(&bcur[b], c);
    }

    // place into chunk-sorted LDS order
    #pragma unroll
    for (int r = 0; r < EPT; ++r) {
        if (br[r] != 0xFFFF) {
            unsigned b = br[r];
            unsigned slot = lscan[b] - lhist[b] + rr[r];
            sbuf[slot] = pr[r];
            sbkt[slot] = (unsigned short)b;
        }
    }
    __syncthreads();

    // coalesced write-out: consecutive slots -> consecutive global positions per bucket run
    for (int slot = t; slot < nval; slot += 256) {
        unsigned p = sbuf[slot];
        unsigned b = sbkt[slot];
        unsigned lst = lscan[b] - lhist[b];
        pairs[gbase[b] + ((unsigned)slot - lst)] = p;
    }
}

// ---------- per-bucket CSR build: row_start + sorted_src ----------
__global__ __launch_bounds__(256)
void build_kernel(const unsigned* __restrict__ pairs, const unsigned* __restrict__ bstart,
                  int* __restrict__ row_start, int* __restrict__ sorted_src) {
    const int b = blockIdx.x;
    const int t = threadIdx.x;
    const int base_node = b << 8;
    const int seg0 = (int)bstart[b], seg1 = (int)bstart[b + 1];
    __shared__ unsigned ldeg[256];
    __shared__ unsigned lsc[256];
    __shared__ int lcur[256];

    ldeg[t] = 0u;
    __syncthreads();
    for (int e = seg0 + t; e < seg1; e += 256)
        atomicAdd(&ldeg[pairs[e] >> 17], 1u);
    __syncthreads();
    lsc[t] = ldeg[t];
    __syncthreads();
    for (int off = 1; off < 256; off <<= 1) {
        unsigned v = (t >= off) ? lsc[t - off] : 0u;
        __syncthreads();
        lsc[t] += v;
        __syncthreads();
    }
    int excl = (int)(lsc[t] - ldeg[t]);
    int node = base_node + t;
    if (node <= N_NODES) row_start[node] = seg0 + excl;
    lcur[t] = seg0 + excl;
    __syncthreads();
    for (int e = seg0 + t; e < seg1; e += 256) {
        unsigned p = pairs[e];
        int pos = atomicAdd(&lcur[p >> 17], 1);
        sorted_src[pos] = (int)(p & 0x1FFFFu);
    }
}

// ---------- fused node linear: q = (x@Wq+bq)*scale; kv interleaved; sk ----------
template <int IN, int OUT>
__global__ __launch_bounds__(256)
void lin_kernel(const float* __restrict__ x,
                const float* __restrict__ Wq, const float* __restrict__ bq,
                const float* __restrict__ Wk, const float* __restrict__ bk,
                const float* __restrict__ Wv, const float* __restrict__ bv,
                const float* __restrict__ Ws, const float* __restrict__ bs,
                float scale,
                float* __restrict__ q, float* __restrict__ kv,
                float* __restrict__ sk, int n)
{
    __shared__ float w[4 * IN * OUT];
    __shared__ float b[4 * OUT];
    for (int t = threadIdx.x; t < IN * OUT; t += blockDim.x) {
        w[t]            = Wq[t];
        w[IN*OUT + t]   = Wk[t];
        w[2*IN*OUT + t] = Wv[t];
        w[3*IN*OUT + t] = Ws[t];
    }
    for (int t = threadIdx.x; t < OUT; t += blockDim.x) {
        b[t]         = bq[t];
        b[OUT + t]   = bk[t];
        b[2*OUT + t] = bv[t];
        b[3*OUT + t] = bs[t];
    }
    __syncthreads();

    for (int i = blockIdx.x * blockDim.x + threadIdx.x; i < n;
         i += gridDim.x * blockDim.x) {
        float xi[IN];
        #pragma unroll
        for (int r = 0; r < IN; ++r) xi[r] = x[(size_t)i * IN + r];

        #pragma unroll
        for (int j = 0; j < OUT; ++j) {
            float aq = b[j], ak = b[OUT + j], av = b[2*OUT + j], as = b[3*OUT + j];
            #pragma unroll
            for (int r = 0; r < IN; ++r) {
                float xr = xi[r];
                aq += xr * w[r*OUT + j];
                ak += xr * w[IN*OUT + r*OUT + j];
                av += xr * w[2*IN*OUT + r*OUT + j];
                as += xr * w[3*IN*OUT + r*OUT + j];
            }
            q[(size_t)i * OUT + j]              = aq * scale;
            kv[(size_t)i * 2 * OUT + j]         = ak;
            kv[(size_t)i * 2 * OUT + OUT + j]   = av;
            sk[(size_t)i * OUT + j]             = as;
        }
    }
}

// ---------- fused per-node attention (float4 lanes, online softmax, unroll-2) ----------
template <int D, bool POOL>
__global__ __launch_bounds__(256)
void fused_attn_kernel(const float* __restrict__ q, const float* __restrict__ kv,
                       const float* __restrict__ sk,
                       const int* __restrict__ row_start, const int* __restrict__ sorted_src,
                       const int* __restrict__ b32, const long long* __restrict__ b64,
                       const int* __restrict__ flag,
                       float* __restrict__ h, float* __restrict__ pool,
                       float* __restrict__ cnt)
{
    constexpr int L = D / 4;             // lanes per group, one float4 each
    const int gpb = 256 / L;
    const int lj = threadIdx.x & (L - 1);
    int i = blockIdx.x * gpb + threadIdx.x / L;
    if (i >= N_NODES) return;

    const float4 qj = *(const float4*)(q + (size_t)i * D + lj * 4);
    const int beg = row_start[i], end = row_start[i + 1];

    float m = -INFINITY, denom = 0.f;
    float4 acc = make_float4(0.f, 0.f, 0.f, 0.f);

    for (int e = beg; e < end; e += 2) {
        int s0 = sorted_src[e];
        int s1 = (e + 1 < end) ? sorted_src[e + 1] : s0;
        const float4* kv0 = (const float4*)(kv + (size_t)s0 * (2 * D));
        const float4* kv1 = (const float4*)(kv + (size_t)s1 * (2 * D));
        float4 k0 = kv0[lj],     k1 = kv1[lj];
        float4 v0 = kv0[L + lj], v1 = kv1[L + lj];

        float p0 = k0.x*qj.x + k0.y*qj.y + k0.z*qj.z + k0.w*qj.w;
        float p1 = k1.x*qj.x + k1.y*qj.y + k1.z*qj.z + k1.w*qj.w;
        #pragma unroll
        for (int off = L / 2; off; off >>= 1) {
            p0 += __shfl_xor(p0, off, L);
            p1 += __shfl_xor(p1, off, L);
        }
        if (e + 1 >= end) p1 = -INFINITY;

        float mn = fmaxf(m, fmaxf(p0, p1));
        float so = __expf(m  - mn);     // first iter: exp(-inf)=0
        float e0 = __expf(p0 - mn);
        float e1 = __expf(p1 - mn);
        denom = denom * so + e0 + e1;
        acc.x = acc.x * so + e0 * v0.x + e1 * v1.x;
        acc.y = acc.y * so + e0 * v0.y + e1 * v1.y;
        acc.z = acc.z * so + e0 * v0.z + e1 * v1.z;
        acc.w = acc.w * so + e0 * v0.w + e1 * v1.w;
        m = mn;
    }

    float dn = 1.f / fmaxf(denom, 1e-16f);
    const float4 skv = *(const float4*)(sk + (size_t)i * D + lj * 4);
    float4 o;
    o.x = fmaxf(acc.x * dn + skv.x, 0.f);
    o.y = fmaxf(acc.y * dn + skv.y, 0.f);
    o.z = fmaxf(acc.z * dn + skv.z, 0.f);
    o.w = fmaxf(acc.w * dn + skv.w, 0.f);

    if (POOL) {
        int b = (*flag) ? (int)b64[i] : b32[i];
        float* pb = pool + b * 32 + lj * 4;
        atomicAdd(pb + 0, o.x);
        atomicAdd(pb + 1, o.y);
        atomicAdd(pb + 2, o.z);
        atomicAdd(pb + 3, o.w);
        if (lj == 0) atomicAdd(&cnt[b], 1.f);
    } else {
        *(float4*)(h + (size_t)i * D + lj * 4) = o;
    }
}

// ---------- final MLP: out = relu(mean @ Wf1 + bf1) @ Wf2 + bf2 ----------
__global__ __launch_bounds__(64)
void mlp_kernel(const float* __restrict__ pool, const float* __restrict__ cnt,
                const float* __restrict__ Wf1, const float* __restrict__ bf1,
                const float* __restrict__ Wf2, const float* __restrict__ bf2,
                float* __restrict__ out)
{
    int g = blockIdx.x;
    int h = threadIdx.x;            // 64 threads = 64 hidden units
    __shared__ float m[32];
    if (h < 32) {
        float c = fmaxf(cnt[g], 1.f);
        m[h] = pool[g * 32 + h] / c;
    }
    __syncthreads();
    float acc = bf1[h];
    #pragma unroll
    for (int r = 0; r < 32; ++r) acc += m[r] * Wf1[r * 64 + h];
    float hid = fmaxf(acc, 0.f);
    float c = hid * Wf2[h];
    #pragma unroll
    for (int off = 32; off; off >>= 1) c += __shfl_xor(c, off, 64);
    if (h == 0) out[g] = c + bf2[0];
}

extern "C" void kernel_launch(void* const* d_in, const int* in_sizes, int n_in,
                              void* d_out, int out_size, void* d_ws, size_t ws_size,
                              hipStream_t stream) {
    const float* x = (const float*)d_in[0];
    const void*  edge_index = d_in[1];
    const void*  batch      = d_in[2];
    const float* Wq1 = (const float*)d_in[3];  const float* bq1 = (const float*)d_in[4];
    const float* Wk1 = (const float*)d_in[5];  const float* bk1 = (const float*)d_in[6];
    const float* Wv1 = (const float*)d_in[7];  const float* bv1 = (const float*)d_in[8];
    const float* Ws1 = (const float*)d_in[9];  const float* bs1 = (const float*)d_in[10];
    const float* Wq2 = (const float*)d_in[11]; const float* bq2 = (const float*)d_in[12];
    const float* Wk2 = (const float*)d_in[13]; const float* bk2 = (const float*)d_in[14];
    const float* Wv2 = (const float*)d_in[15]; const float* bv2 = (const float*)d_in[16];
    const float* Ws2 = (const float*)d_in[17]; const float* bs2 = (const float*)d_in[18];
    const float* Wf1 = (const float*)d_in[19]; const float* bf1 = (const float*)d_in[20];
    const float* Wf2 = (const float*)d_in[21]; const float* bf2 = (const float*)d_in[22];
    float* out = (float*)d_out;

    // ---------------- workspace layout ----------------
    char* ws = (char*)d_ws;
    size_t off = 0;
    auto carve = [&](size_t bytes) {
        char* p = ws + off;
        off = (off + bytes + 255) & ~(size_t)255;
        return p;
    };
    int*      flag     = (int*)      carve(16);
    float*    qb       = (float*)    carve((size_t)N_NODES * 32 * 4);
    float*    kvb      = (float*)    carve((size_t)N_NODES * 64 * 4);
    float*    skb      = (float*)    carve((size_t)N_NODES * 32 * 4);
    float*    h1       = (float*)    carve((size_t)N_NODES * 16 * 4);
    unsigned* pairs    = (unsigned*) carve((size_t)N_EDGES * 4);
    int*      srt_src  = (int*)      carve((size_t)N_EDGES * 4);
    int*      row_start= (int*)      carve((size_t)(N_NODES + 1) * 4);
    unsigned* bcnt     = (unsigned*) carve((size_t)NBKT * 4);
    unsigned* bstart   = (unsigned*) carve((size_t)(NBKT + 1) * 4);
    unsigned* bcur     = (unsigned*) carve((size_t)NBKT * 4);
    float*    pool     = (float*)    carve((size_t)N_GRAPHS * 32 * 4);
    float*    cnt      = (float*)    carve((size_t)N_GRAPHS * 4);
    (void)ws_size; (void)in_sizes; (void)n_in; (void)out_size;

    const int* ei32 = (const int*)edge_index;
    const long long* ei64 = (const long long*)edge_index;
    const int* b32 = (const int*)batch;
    const long long* b64 = (const long long*)batch;

    const dim3 blk(256);

    // ---- CSR build (two-level bucket sort; shared by both layers) ----
    detect_kernel<<<1, 64, 0, stream>>>(ei64, flag);
    zero_kernel<<<(N_GRAPHS * 32 + 255) / 256, blk, 0, stream>>>(bcnt, pool, cnt);
    bhist_kernel<<<512, blk, 0, stream>>>(ei32, ei64, flag, bcnt);
    bscan_kernel<<<1, 512, 0, stream>>>(bcnt, bstart, bcur);
    partition_kernel<<<(N_EDGES + PCHUNK - 1) / PCHUNK, blk, 0, stream>>>(
        ei32, ei64, flag, bcur, pairs);
    build_kernel<<<NBKT, blk, 0, stream>>>(pairs, bstart, row_start, srt_src);

    // ---- layer 1 (11 -> 16) ----
    lin_kernel<11, 16><<<(N_NODES + 255) / 256, blk, 0, stream>>>(
        x, Wq1, bq1, Wk1, bk1, Wv1, bv1, Ws1, bs1, 0.25f,
        qb, kvb, skb, N_NODES);
    fused_attn_kernel<16, false><<<(N_NODES + 63) / 64, blk, 0, stream>>>(
        qb, kvb, skb, row_start, srt_src, b32, b64, flag, h1, pool, cnt);

    // ---- layer 2 (16 -> 32), pooling fused into epilogue ----
    lin_kernel<16, 32><<<(N_NODES + 255) / 256, blk, 0, stream>>>(
        h1, Wq2, bq2, Wk2, bk2, Wv2, bv2, Ws2, bs2, 0.17677669529663688f,
        qb, kvb, skb, N_NODES);
    fused_attn_kernel<32, true><<<(N_NODES + 31) / 32, blk, 0, stream>>>(
        qb, kvb, skb, row_start, srt_src, b32, b64, flag, nullptr, pool, cnt);

    // ---- MLP head ----
    mlp_kernel<<<N_GRAPHS, 64, 0, stream>>>(pool, cnt, Wf1, bf1, Wf2, bf2, out);
}